// Round 5
// baseline (774.092 us; speedup 1.0000x reference)
//
#include <hip/hip_runtime.h>
#include <math.h>

#define FDIM 128
#define RPB 128      // rows per bucket (bucket = id >> 7)
#define BSTRIDE 32   // ints per bucket counter (128 B) — one cache line per counter

// ---------------- CSR build (fully bucketed; no N-wide random atomics) ----------------

__global__ __launch_bounds__(256) void k_zero(int* rbCnt, int* cbCnt, int nbs) {
    int i = blockIdx.x * 256 + threadIdx.x;
    if (i < nbs) { rbCnt[i] = 0; cbCnt[i] = 0; }
}

// bucket-level counts: 782 padded counters per side, atomic traffic stays in-cache
__global__ __launch_bounds__(256) void k_bcnt(const int* __restrict__ row, const int* __restrict__ col,
                                              int* rbCnt, int* cbCnt, int nE) {
    int e = blockIdx.x * 256 + threadIdx.x;
    if (e < nE) {
        atomicAdd(&rbCnt[(size_t)(row[e] >> 7) * BSTRIDE], 1);
        atomicAdd(&cbCnt[(size_t)(col[e] >> 7) * BSTRIDE], 1);
    }
}

// one-block exclusive scan of both bucket-count arrays; seeds bases and cursors
__global__ __launch_bounds__(1024) void k_bscan(const int* __restrict__ rbCnt, const int* __restrict__ cbCnt,
                                                int* rbBase, int* cbBase, int* rbCur, int* cbCur,
                                                int nb, int nE) {
    __shared__ int s[1024];
    int tid = threadIdx.x;
    // row side
    int v = (tid < nb) ? rbCnt[(size_t)tid * BSTRIDE] : 0;
    s[tid] = v;
    __syncthreads();
    for (int off = 1; off < 1024; off <<= 1) {
        int t = (tid >= off) ? s[tid - off] : 0;
        __syncthreads();
        s[tid] += t;
        __syncthreads();
    }
    if (tid < nb) {
        int ex = s[tid] - v;
        rbBase[tid] = ex;
        rbCur[(size_t)tid * BSTRIDE] = ex;
    }
    if (tid == 0) rbBase[nb] = nE;
    __syncthreads();
    // col side
    v = (tid < nb) ? cbCnt[(size_t)tid * BSTRIDE] : 0;
    s[tid] = v;
    __syncthreads();
    for (int off = 1; off < 1024; off <<= 1) {
        int t = (tid >= off) ? s[tid - off] : 0;
        __syncthreads();
        s[tid] += t;
        __syncthreads();
    }
    if (tid < nb) {
        int ex = s[tid] - v;
        cbBase[tid] = ex;
        cbCur[(size_t)tid * BSTRIDE] = ex;
    }
    if (tid == 0) cbBase[nb] = nE;
}

// scatter edges into row-buckets (packed pair) and col-buckets (local col byte)
__global__ __launch_bounds__(256) void k_bucket2(const int* __restrict__ row, const int* __restrict__ col,
                                                 int* rbCur, int* cbCur,
                                                 unsigned int* __restrict__ pairs,
                                                 unsigned char* __restrict__ clocal, int nE) {
    int e = blockIdx.x * 256 + threadIdx.x;
    if (e < nE) {
        int r = row[e];
        int c = col[e];
        int pos = atomicAdd(&rbCur[(size_t)(r >> 7) * BSTRIDE], 1);
        pairs[pos] = ((unsigned int)(r & (RPB - 1)) << 25) | (unsigned int)c;
        int pos2 = atomicAdd(&cbCur[(size_t)(c >> 7) * BSTRIDE], 1);
        clocal[pos2] = (unsigned char)(c & (RPB - 1));
    }
}

// per row-bucket: LDS histogram -> LDS scan -> row_ptr (coalesced) + csr_col placement
__global__ __launch_bounds__(256) void k_rowsort(const int* __restrict__ rbBase,
                                                 const unsigned int* __restrict__ pairs,
                                                 int* __restrict__ row_ptr, int* __restrict__ csr_col,
                                                 int n, int nb) {
    __shared__ int hist[RPB];
    __shared__ int scan[RPB];
    __shared__ int lcur[RPB];
    const int b = blockIdx.x;
    const int tid = threadIdx.x;
    const int row0 = b * RPB;
    const int start = rbBase[b];
    const int endp = rbBase[b + 1];

    if (tid < RPB) hist[tid] = 0;
    __syncthreads();
    for (int i = start + tid; i < endp; i += 256)
        atomicAdd(&hist[pairs[i] >> 25], 1);
    __syncthreads();

    // inclusive scan over 128 bins
    if (tid < RPB) scan[tid] = hist[tid];
    __syncthreads();
    for (int off = 1; off < RPB; off <<= 1) {
        int t = (tid < RPB && tid >= off) ? scan[tid - off] : 0;
        __syncthreads();
        if (tid < RPB) scan[tid] += t;
        __syncthreads();
    }
    if (tid < RPB) {
        int ex = start + scan[tid] - hist[tid];  // exclusive + bucket base
        lcur[tid] = ex;
        int r = row0 + tid;
        if (r < n) row_ptr[r] = ex;
    }
    if (b == nb - 1 && tid == 0) row_ptr[n] = endp;
    __syncthreads();

    for (int i = start + tid; i < endp; i += 256) {
        unsigned int u = pairs[i];
        int pos = atomicAdd(&lcur[u >> 25], 1);
        csr_col[pos] = (int)(u & 0x1FFFFFFu);
    }
}

// per col-bucket: LDS histogram of local col bytes -> dinv directly
__global__ __launch_bounds__(256) void k_colhist(const int* __restrict__ cbBase,
                                                 const unsigned char* __restrict__ clocal,
                                                 float* __restrict__ dinv, int n) {
    __shared__ int hist[RPB];
    const int b = blockIdx.x;
    const int tid = threadIdx.x;
    const int start = cbBase[b];
    const int endp = cbBase[b + 1];
    if (tid < RPB) hist[tid] = 0;
    __syncthreads();
    for (int i = start + tid; i < endp; i += 256)
        atomicAdd(&hist[(int)clocal[i]], 1);
    __syncthreads();
    if (tid < RPB) {
        int c = b * RPB + tid;
        if (c < n) dinv[c] = rsqrtf((float)hist[tid] + 1.0f);
    }
}

// ---------------- GEMM: out[r][c] = (sum_k X[r][k]*W[k][c] + bias[c]) * dinv[r] ----------------
// 64 rows x 128 cols per block, 256 threads, 4x8 acc per thread, k-tile 32.

__global__ __launch_bounds__(256) void k_gemm(const float* __restrict__ X, const float* __restrict__ W,
                                              const float* __restrict__ bias, const float* __restrict__ dinv,
                                              float* __restrict__ out, int nRows) {
    __shared__ float sX[32][68];   // [k][row], padded
    __shared__ float sW[32][132];  // [k][col], padded

    const int tid = threadIdx.x;
    const int row0 = blockIdx.x * 64;
    const int rb = (tid >> 4) * 4;   // 0..60
    const int cb = (tid & 15) * 8;   // 0..120

    float acc[4][8];
#pragma unroll
    for (int i = 0; i < 4; i++)
#pragma unroll
        for (int j = 0; j < 8; j++) acc[i][j] = 0.0f;

    for (int k0 = 0; k0 < FDIM; k0 += 32) {
#pragma unroll
        for (int it = 0; it < 2; it++) {
            int f = tid + it * 256;
            int r = f >> 3;
            int kq = (f & 7) * 4;
            float4 v = make_float4(0.f, 0.f, 0.f, 0.f);
            int gr = row0 + r;
            if (gr < nRows) v = *(const float4*)&X[(size_t)gr * FDIM + k0 + kq];
            sX[kq + 0][r] = v.x;
            sX[kq + 1][r] = v.y;
            sX[kq + 2][r] = v.z;
            sX[kq + 3][r] = v.w;
        }
#pragma unroll
        for (int it = 0; it < 4; it++) {
            int f = tid + it * 256;
            int k = f >> 5;
            int cq = (f & 31) * 4;
            float4 v = *(const float4*)&W[(size_t)(k0 + k) * FDIM + cq];
            *(float4*)&sW[k][cq] = v;
        }
        __syncthreads();
#pragma unroll 4
        for (int kk = 0; kk < 32; kk++) {
            float4 xv = *(const float4*)&sX[kk][rb];
            float wv[8];
            *(float4*)&wv[0] = *(const float4*)&sW[kk][cb];
            *(float4*)&wv[4] = *(const float4*)&sW[kk][cb + 4];
            float xs[4] = {xv.x, xv.y, xv.z, xv.w};
#pragma unroll
            for (int i = 0; i < 4; i++)
#pragma unroll
                for (int j = 0; j < 8; j++) acc[i][j] += xs[i] * wv[j];
        }
        __syncthreads();
    }

    float bv[8];
    *(float4*)&bv[0] = *(const float4*)&bias[cb];
    *(float4*)&bv[4] = *(const float4*)&bias[cb + 4];

#pragma unroll
    for (int i = 0; i < 4; i++) {
        int gr = row0 + rb + i;
        if (gr < nRows) {
            float di = dinv[gr];
            float4 o0, o1;
            o0.x = (acc[i][0] + bv[0]) * di;
            o0.y = (acc[i][1] + bv[1]) * di;
            o0.z = (acc[i][2] + bv[2]) * di;
            o0.w = (acc[i][3] + bv[3]) * di;
            o1.x = (acc[i][4] + bv[4]) * di;
            o1.y = (acc[i][5] + bv[5]) * di;
            o1.z = (acc[i][6] + bv[6]) * di;
            o1.w = (acc[i][7] + bv[7]) * di;
            *(float4*)&out[(size_t)gr * FDIM + cb] = o0;
            *(float4*)&out[(size_t)gr * FDIM + cb + 4] = o1;
        }
    }
}

// ---------------- Aggregation: out[i] = dinv[i]*(hs[i] + sum_{e in row i} hs[col[e]]) ----------------

__global__ __launch_bounds__(256) void k_agg(const float* __restrict__ hs, const int* __restrict__ row_ptr,
                                             const int* __restrict__ csr_col, const float* __restrict__ dinv,
                                             float* __restrict__ out, int n, int relu) {
    int w = (blockIdx.x * 256 + threadIdx.x) >> 6;
    int lane = threadIdx.x & 63;
    if (w >= n) return;
    const float2* hs2 = (const float2*)hs;
    float2 v = hs2[(size_t)w * 64 + lane];
    float a0 = v.x, a1 = v.y;

    int e = row_ptr[w];
    const int end = row_ptr[w + 1];

    while (e < end) {
        int cnt = end - e;
        if (cnt > 64) cnt = 64;
        int jv = (e + lane < end) ? csr_col[e + lane] : 0;
        int t = 0;
        for (; t + 8 <= cnt; t += 8) {
            int j0 = __shfl(jv, t + 0, 64);
            int j1 = __shfl(jv, t + 1, 64);
            int j2 = __shfl(jv, t + 2, 64);
            int j3 = __shfl(jv, t + 3, 64);
            int j4 = __shfl(jv, t + 4, 64);
            int j5 = __shfl(jv, t + 5, 64);
            int j6 = __shfl(jv, t + 6, 64);
            int j7 = __shfl(jv, t + 7, 64);
            float2 u0 = hs2[(size_t)j0 * 64 + lane];
            float2 u1 = hs2[(size_t)j1 * 64 + lane];
            float2 u2 = hs2[(size_t)j2 * 64 + lane];
            float2 u3 = hs2[(size_t)j3 * 64 + lane];
            float2 u4 = hs2[(size_t)j4 * 64 + lane];
            float2 u5 = hs2[(size_t)j5 * 64 + lane];
            float2 u6 = hs2[(size_t)j6 * 64 + lane];
            float2 u7 = hs2[(size_t)j7 * 64 + lane];
            a0 += ((u0.x + u1.x) + (u2.x + u3.x)) + ((u4.x + u5.x) + (u6.x + u7.x));
            a1 += ((u0.y + u1.y) + (u2.y + u3.y)) + ((u4.y + u5.y) + (u6.y + u7.y));
        }
        for (; t < cnt; t++) {
            int j = __shfl(jv, t, 64);
            float2 u = hs2[(size_t)j * 64 + lane];
            a0 += u.x;
            a1 += u.y;
        }
        e += cnt;
    }

    float di = dinv[w];
    a0 *= di;
    a1 *= di;
    if (relu) {
        a0 = fmaxf(a0, 0.0f);
        a1 = fmaxf(a1, 0.0f);
    }
    ((float2*)out)[(size_t)w * 64 + lane] = make_float2(a0, a1);
}

// ---------------- log_softmax (in place), one wave per row ----------------

__global__ __launch_bounds__(256) void k_lsm(float* data, int n) {
    int w = (blockIdx.x * 256 + threadIdx.x) >> 6;
    int lane = threadIdx.x & 63;
    if (w >= n) return;
    float2* p = (float2*)data;
    float2 v = p[(size_t)w * 64 + lane];
    float m = fmaxf(v.x, v.y);
#pragma unroll
    for (int off = 32; off > 0; off >>= 1) m = fmaxf(m, __shfl_xor(m, off, 64));
    float s = expf(v.x - m) + expf(v.y - m);
#pragma unroll
    for (int off = 32; off > 0; off >>= 1) s += __shfl_xor(s, off, 64);
    float lg = m + logf(s);
    p[(size_t)w * 64 + lane] = make_float2(v.x - lg, v.y - lg);
}

// ---------------- launch ----------------

extern "C" void kernel_launch(void* const* d_in, const int* in_sizes, int n_in,
                              void* d_out, int out_size, void* d_ws, size_t ws_size,
                              hipStream_t stream) {
    const float* x  = (const float*)d_in[0];
    const float* W0 = (const float*)d_in[1];
    const float* b0 = (const float*)d_in[2];
    const float* W1 = (const float*)d_in[3];
    const float* b1 = (const float*)d_in[4];
    const int* row  = (const int*)d_in[5];
    const int* col  = (const int*)d_in[6];
    float* out = (float*)d_out;

    const int N = in_sizes[0] / FDIM;
    const int E = in_sizes[5];
    const int NB = (N + RPB - 1) / RPB;  // buckets (782 for N=100000)

    char* w = (char*)d_ws;
    size_t off = 0;
    auto alloc = [&](size_t bytes) {
        char* p = w + off;
        off += (bytes + 255) & ~(size_t)255;
        return p;
    };
    int* rbCnt   = (int*)alloc((size_t)NB * BSTRIDE * 4);
    int* cbCnt   = (int*)alloc((size_t)NB * BSTRIDE * 4);
    int* rbCur   = (int*)alloc((size_t)NB * BSTRIDE * 4);
    int* cbCur   = (int*)alloc((size_t)NB * BSTRIDE * 4);
    int* rbBase  = (int*)alloc((size_t)(NB + 1) * 4);
    int* cbBase  = (int*)alloc((size_t)(NB + 1) * 4);
    float* dinv  = (float*)alloc((size_t)N * 4);
    int* row_ptr = (int*)alloc((size_t)(N + 1) * 4);
    int* csr_col = (int*)alloc((size_t)E * 4);
    float* bufA  = (float*)alloc((size_t)N * FDIM * 4);
    // pairs/clocal alias bufA: CSR build finishes before the first GEMM writes bufA
    unsigned int* pairs = (unsigned int*)bufA;
    unsigned char* clocal = (unsigned char*)(bufA) + (size_t)E * 4;

    const int gE = (E + 255) / 256;       // edge-grid
    const int gW = (N * 64 + 255) / 256;  // wave-per-node grid
    const int gG = (N + 63) / 64;         // gemm grid
    const int gZ = (NB * BSTRIDE + 255) / 256;

    // CSR build + dinv (fully bucketed)
    k_zero<<<gZ, 256, 0, stream>>>(rbCnt, cbCnt, NB * BSTRIDE);
    k_bcnt<<<gE, 256, 0, stream>>>(row, col, rbCnt, cbCnt, E);
    k_bscan<<<1, 1024, 0, stream>>>(rbCnt, cbCnt, rbBase, cbBase, rbCur, cbCur, NB, E);
    k_bucket2<<<gE, 256, 0, stream>>>(row, col, rbCur, cbCur, pairs, clocal, E);
    k_rowsort<<<NB, 256, 0, stream>>>(rbBase, pairs, row_ptr, csr_col, N, NB);
    k_colhist<<<NB, 256, 0, stream>>>(cbBase, clocal, dinv, N);

    // layer 0: hs0 = (x@W0 + b0)*dinv  -> bufA ; agg -> d_out (with relu)
    k_gemm<<<gG, 256, 0, stream>>>(x, W0, b0, dinv, bufA, N);
    k_agg<<<gW, 256, 0, stream>>>(bufA, row_ptr, csr_col, dinv, out, N, 1);

    // layer 1: hs1 = (out@W1 + b1)*dinv -> bufA ; agg -> d_out (no relu)
    k_gemm<<<gG, 256, 0, stream>>>(out, W1, b1, dinv, bufA, N);
    k_agg<<<gW, 256, 0, stream>>>(bufA, row_ptr, csr_col, dinv, out, N, 0);

    // log_softmax in place on d_out
    k_lsm<<<gW, 256, 0, stream>>>(out, N);
}

// Round 6
// 557.024 us; speedup vs baseline: 1.3897x; 1.3897x over previous
//
#include <hip/hip_runtime.h>
#include <math.h>

#define FDIM 128
#define RPB 128      // rows per bucket (bucket = id >> 7)
#define BSTRIDE 32   // ints per bucket counter (128 B) — one cache line per counter
#define NBLK 256     // blocks in count/scatter multisplit
#define MAXB 1024    // max buckets (N <= 131072)

// ---------------- CSR build: block-reservation multisplit ----------------

__global__ __launch_bounds__(256) void k_zero(int* rbCnt, int* cbCnt, int nbs) {
    int i = blockIdx.x * 256 + threadIdx.x;
    if (i < nbs) { rbCnt[i] = 0; cbCnt[i] = 0; }
}

// per-block LDS histograms over buckets, one padded-counter flush per block
__global__ __launch_bounds__(256) void k_count(const int* __restrict__ row, const int* __restrict__ col,
                                               int* rbCnt, int* cbCnt, int nE, int nb) {
    __shared__ int rh[MAXB];
    __shared__ int ch[MAXB];
    const int tid = threadIdx.x;
    const int cpb = (nE + NBLK - 1) / NBLK;
    const int e0 = blockIdx.x * cpb;
    int e1 = e0 + cpb; if (e1 > nE) e1 = nE;
    for (int i = tid; i < nb; i += 256) { rh[i] = 0; ch[i] = 0; }
    __syncthreads();
    for (int e = e0 + tid; e < e1; e += 256) {
        atomicAdd(&rh[row[e] >> 7], 1);
        atomicAdd(&ch[col[e] >> 7], 1);
    }
    __syncthreads();
    for (int i = tid; i < nb; i += 256) {
        if (rh[i]) atomicAdd(&rbCnt[(size_t)i * BSTRIDE], rh[i]);
        if (ch[i]) atomicAdd(&cbCnt[(size_t)i * BSTRIDE], ch[i]);
    }
}

// one-block exclusive scan of both bucket-count arrays; seeds bases and cursors
__global__ __launch_bounds__(1024) void k_bscan(const int* __restrict__ rbCnt, const int* __restrict__ cbCnt,
                                                int* rbBase, int* cbBase, int* rbCur, int* cbCur,
                                                int nb, int nE) {
    __shared__ int s[1024];
    int tid = threadIdx.x;
    int v = (tid < nb) ? rbCnt[(size_t)tid * BSTRIDE] : 0;
    s[tid] = v;
    __syncthreads();
    for (int off = 1; off < 1024; off <<= 1) {
        int t = (tid >= off) ? s[tid - off] : 0;
        __syncthreads();
        s[tid] += t;
        __syncthreads();
    }
    if (tid < nb) {
        int ex = s[tid] - v;
        rbBase[tid] = ex;
        rbCur[(size_t)tid * BSTRIDE] = ex;
    }
    if (tid == 0) rbBase[nb] = nE;
    __syncthreads();
    v = (tid < nb) ? cbCnt[(size_t)tid * BSTRIDE] : 0;
    s[tid] = v;
    __syncthreads();
    for (int off = 1; off < 1024; off <<= 1) {
        int t = (tid >= off) ? s[tid - off] : 0;
        __syncthreads();
        s[tid] += t;
        __syncthreads();
    }
    if (tid < nb) {
        int ex = s[tid] - v;
        cbBase[tid] = ex;
        cbCur[(size_t)tid * BSTRIDE] = ex;
    }
    if (tid == 0) cbBase[nb] = nE;
}

// block-reservation scatter: LDS histogram -> one global reservation per
// (block,bucket) -> contiguous runs per bucket. Runs make sector writes
// mostly single-producer (kills cross-XCD partial-line write-back churn).
__global__ __launch_bounds__(256) void k_scatter2(const int* __restrict__ row, const int* __restrict__ col,
                                                  int* rbCur, int* cbCur,
                                                  unsigned int* __restrict__ pairs,
                                                  unsigned char* __restrict__ clocal, int nE, int nb) {
    __shared__ int rh[MAXB];
    __shared__ int ch[MAXB];
    __shared__ int rbase[MAXB];
    __shared__ int cbase[MAXB];
    const int tid = threadIdx.x;
    const int cpb = (nE + NBLK - 1) / NBLK;
    const int e0 = blockIdx.x * cpb;
    int e1 = e0 + cpb; if (e1 > nE) e1 = nE;

    for (int i = tid; i < nb; i += 256) { rh[i] = 0; ch[i] = 0; }
    __syncthreads();
    for (int e = e0 + tid; e < e1; e += 256) {
        atomicAdd(&rh[row[e] >> 7], 1);
        atomicAdd(&ch[col[e] >> 7], 1);
    }
    __syncthreads();
    for (int i = tid; i < nb; i += 256) {
        rbase[i] = rh[i] ? atomicAdd(&rbCur[(size_t)i * BSTRIDE], rh[i]) : 0;
        cbase[i] = ch[i] ? atomicAdd(&cbCur[(size_t)i * BSTRIDE], ch[i]) : 0;
        rh[i] = 0;
        ch[i] = 0;
    }
    __syncthreads();
    for (int e = e0 + tid; e < e1; e += 256) {
        int r = row[e];
        int c = col[e];
        int rb = r >> 7, cb = c >> 7;
        int p = rbase[rb] + atomicAdd(&rh[rb], 1);
        pairs[p] = ((unsigned int)(r & (RPB - 1)) << 25) | (unsigned int)c;
        int q = cbase[cb] + atomicAdd(&ch[cb], 1);
        clocal[q] = (unsigned char)(c & (RPB - 1));
    }
}

// per row-bucket: LDS histogram -> LDS scan -> row_ptr (coalesced) + csr_col placement
__global__ __launch_bounds__(256) void k_rowsort(const int* __restrict__ rbBase,
                                                 const unsigned int* __restrict__ pairs,
                                                 int* __restrict__ row_ptr, int* __restrict__ csr_col,
                                                 int n, int nb) {
    __shared__ int hist[RPB];
    __shared__ int scan[RPB];
    __shared__ int lcur[RPB];
    const int b = blockIdx.x;
    const int tid = threadIdx.x;
    const int row0 = b * RPB;
    const int start = rbBase[b];
    const int endp = rbBase[b + 1];

    if (tid < RPB) hist[tid] = 0;
    __syncthreads();
    for (int i = start + tid; i < endp; i += 256)
        atomicAdd(&hist[pairs[i] >> 25], 1);
    __syncthreads();

    if (tid < RPB) scan[tid] = hist[tid];
    __syncthreads();
    for (int off = 1; off < RPB; off <<= 1) {
        int t = (tid < RPB && tid >= off) ? scan[tid - off] : 0;
        __syncthreads();
        if (tid < RPB) scan[tid] += t;
        __syncthreads();
    }
    if (tid < RPB) {
        int ex = start + scan[tid] - hist[tid];
        lcur[tid] = ex;
        int r = row0 + tid;
        if (r < n) row_ptr[r] = ex;
    }
    if (b == nb - 1 && tid == 0) row_ptr[n] = endp;
    __syncthreads();

    for (int i = start + tid; i < endp; i += 256) {
        unsigned int u = pairs[i];
        int pos = atomicAdd(&lcur[u >> 25], 1);
        csr_col[pos] = (int)(u & 0x1FFFFFFu);
    }
}

// per col-bucket: LDS histogram of local col bytes -> dinv directly
__global__ __launch_bounds__(256) void k_colhist(const int* __restrict__ cbBase,
                                                 const unsigned char* __restrict__ clocal,
                                                 float* __restrict__ dinv, int n) {
    __shared__ int hist[RPB];
    const int b = blockIdx.x;
    const int tid = threadIdx.x;
    const int start = cbBase[b];
    const int endp = cbBase[b + 1];
    if (tid < RPB) hist[tid] = 0;
    __syncthreads();
    for (int i = start + tid; i < endp; i += 256)
        atomicAdd(&hist[(int)clocal[i]], 1);
    __syncthreads();
    if (tid < RPB) {
        int c = b * RPB + tid;
        if (c < n) dinv[c] = rsqrtf((float)hist[tid] + 1.0f);
    }
}

// ---------------- GEMM: out[r][c] = (sum_k X[r][k]*W[k][c] + bias[c]) * dinv[r] ----------------

__global__ __launch_bounds__(256) void k_gemm(const float* __restrict__ X, const float* __restrict__ W,
                                              const float* __restrict__ bias, const float* __restrict__ dinv,
                                              float* __restrict__ out, int nRows) {
    __shared__ float sX[32][68];   // [k][row], padded
    __shared__ float sW[32][132];  // [k][col], padded

    const int tid = threadIdx.x;
    const int row0 = blockIdx.x * 64;
    const int rb = (tid >> 4) * 4;   // 0..60
    const int cb = (tid & 15) * 8;   // 0..120

    float acc[4][8];
#pragma unroll
    for (int i = 0; i < 4; i++)
#pragma unroll
        for (int j = 0; j < 8; j++) acc[i][j] = 0.0f;

    for (int k0 = 0; k0 < FDIM; k0 += 32) {
#pragma unroll
        for (int it = 0; it < 2; it++) {
            int f = tid + it * 256;
            int r = f >> 3;
            int kq = (f & 7) * 4;
            float4 v = make_float4(0.f, 0.f, 0.f, 0.f);
            int gr = row0 + r;
            if (gr < nRows) v = *(const float4*)&X[(size_t)gr * FDIM + k0 + kq];
            sX[kq + 0][r] = v.x;
            sX[kq + 1][r] = v.y;
            sX[kq + 2][r] = v.z;
            sX[kq + 3][r] = v.w;
        }
#pragma unroll
        for (int it = 0; it < 4; it++) {
            int f = tid + it * 256;
            int k = f >> 5;
            int cq = (f & 31) * 4;
            float4 v = *(const float4*)&W[(size_t)(k0 + k) * FDIM + cq];
            *(float4*)&sW[k][cq] = v;
        }
        __syncthreads();
#pragma unroll 4
        for (int kk = 0; kk < 32; kk++) {
            float4 xv = *(const float4*)&sX[kk][rb];
            float wv[8];
            *(float4*)&wv[0] = *(const float4*)&sW[kk][cb];
            *(float4*)&wv[4] = *(const float4*)&sW[kk][cb + 4];
            float xs[4] = {xv.x, xv.y, xv.z, xv.w};
#pragma unroll
            for (int i = 0; i < 4; i++)
#pragma unroll
                for (int j = 0; j < 8; j++) acc[i][j] += xs[i] * wv[j];
        }
        __syncthreads();
    }

    float bv[8];
    *(float4*)&bv[0] = *(const float4*)&bias[cb];
    *(float4*)&bv[4] = *(const float4*)&bias[cb + 4];

#pragma unroll
    for (int i = 0; i < 4; i++) {
        int gr = row0 + rb + i;
        if (gr < nRows) {
            float di = dinv[gr];
            float4 o0, o1;
            o0.x = (acc[i][0] + bv[0]) * di;
            o0.y = (acc[i][1] + bv[1]) * di;
            o0.z = (acc[i][2] + bv[2]) * di;
            o0.w = (acc[i][3] + bv[3]) * di;
            o1.x = (acc[i][4] + bv[4]) * di;
            o1.y = (acc[i][5] + bv[5]) * di;
            o1.z = (acc[i][6] + bv[6]) * di;
            o1.w = (acc[i][7] + bv[7]) * di;
            *(float4*)&out[(size_t)gr * FDIM + cb] = o0;
            *(float4*)&out[(size_t)gr * FDIM + cb + 4] = o1;
        }
    }
}

// ---------------- Aggregation: out[i] = dinv[i]*(hs[i] + sum_{e in row i} hs[col[e]]) ----------------

__global__ __launch_bounds__(256) void k_agg(const float* __restrict__ hs, const int* __restrict__ row_ptr,
                                             const int* __restrict__ csr_col, const float* __restrict__ dinv,
                                             float* __restrict__ out, int n, int relu) {
    int w = (blockIdx.x * 256 + threadIdx.x) >> 6;
    int lane = threadIdx.x & 63;
    if (w >= n) return;
    const float2* hs2 = (const float2*)hs;
    float2 v = hs2[(size_t)w * 64 + lane];
    float a0 = v.x, a1 = v.y;

    int e = row_ptr[w];
    const int end = row_ptr[w + 1];

    while (e < end) {
        int cnt = end - e;
        if (cnt > 64) cnt = 64;
        int jv = (e + lane < end) ? csr_col[e + lane] : 0;
        int t = 0;
        for (; t + 8 <= cnt; t += 8) {
            int j0 = __shfl(jv, t + 0, 64);
            int j1 = __shfl(jv, t + 1, 64);
            int j2 = __shfl(jv, t + 2, 64);
            int j3 = __shfl(jv, t + 3, 64);
            int j4 = __shfl(jv, t + 4, 64);
            int j5 = __shfl(jv, t + 5, 64);
            int j6 = __shfl(jv, t + 6, 64);
            int j7 = __shfl(jv, t + 7, 64);
            float2 u0 = hs2[(size_t)j0 * 64 + lane];
            float2 u1 = hs2[(size_t)j1 * 64 + lane];
            float2 u2 = hs2[(size_t)j2 * 64 + lane];
            float2 u3 = hs2[(size_t)j3 * 64 + lane];
            float2 u4 = hs2[(size_t)j4 * 64 + lane];
            float2 u5 = hs2[(size_t)j5 * 64 + lane];
            float2 u6 = hs2[(size_t)j6 * 64 + lane];
            float2 u7 = hs2[(size_t)j7 * 64 + lane];
            a0 += ((u0.x + u1.x) + (u2.x + u3.x)) + ((u4.x + u5.x) + (u6.x + u7.x));
            a1 += ((u0.y + u1.y) + (u2.y + u3.y)) + ((u4.y + u5.y) + (u6.y + u7.y));
        }
        for (; t < cnt; t++) {
            int j = __shfl(jv, t, 64);
            float2 u = hs2[(size_t)j * 64 + lane];
            a0 += u.x;
            a1 += u.y;
        }
        e += cnt;
    }

    float di = dinv[w];
    a0 *= di;
    a1 *= di;
    if (relu) {
        a0 = fmaxf(a0, 0.0f);
        a1 = fmaxf(a1, 0.0f);
    }
    ((float2*)out)[(size_t)w * 64 + lane] = make_float2(a0, a1);
}

// ---------------- log_softmax (in place), one wave per row ----------------

__global__ __launch_bounds__(256) void k_lsm(float* data, int n) {
    int w = (blockIdx.x * 256 + threadIdx.x) >> 6;
    int lane = threadIdx.x & 63;
    if (w >= n) return;
    float2* p = (float2*)data;
    float2 v = p[(size_t)w * 64 + lane];
    float m = fmaxf(v.x, v.y);
#pragma unroll
    for (int off = 32; off > 0; off >>= 1) m = fmaxf(m, __shfl_xor(m, off, 64));
    float s = expf(v.x - m) + expf(v.y - m);
#pragma unroll
    for (int off = 32; off > 0; off >>= 1) s += __shfl_xor(s, off, 64);
    float lg = m + logf(s);
    p[(size_t)w * 64 + lane] = make_float2(v.x - lg, v.y - lg);
}

// ---------------- launch ----------------

extern "C" void kernel_launch(void* const* d_in, const int* in_sizes, int n_in,
                              void* d_out, int out_size, void* d_ws, size_t ws_size,
                              hipStream_t stream) {
    const float* x  = (const float*)d_in[0];
    const float* W0 = (const float*)d_in[1];
    const float* b0 = (const float*)d_in[2];
    const float* W1 = (const float*)d_in[3];
    const float* b1 = (const float*)d_in[4];
    const int* row  = (const int*)d_in[5];
    const int* col  = (const int*)d_in[6];
    float* out = (float*)d_out;

    const int N = in_sizes[0] / FDIM;
    const int E = in_sizes[5];
    const int NB = (N + RPB - 1) / RPB;  // buckets (782 for N=100000)

    char* w = (char*)d_ws;
    size_t off = 0;
    auto alloc = [&](size_t bytes) {
        char* p = w + off;
        off += (bytes + 255) & ~(size_t)255;
        return p;
    };
    int* rbCnt   = (int*)alloc((size_t)NB * BSTRIDE * 4);
    int* cbCnt   = (int*)alloc((size_t)NB * BSTRIDE * 4);
    int* rbCur   = (int*)alloc((size_t)NB * BSTRIDE * 4);
    int* cbCur   = (int*)alloc((size_t)NB * BSTRIDE * 4);
    int* rbBase  = (int*)alloc((size_t)(NB + 1) * 4);
    int* cbBase  = (int*)alloc((size_t)(NB + 1) * 4);
    float* dinv  = (float*)alloc((size_t)N * 4);
    int* row_ptr = (int*)alloc((size_t)(N + 1) * 4);
    int* csr_col = (int*)alloc((size_t)E * 4);
    float* bufA  = (float*)alloc((size_t)N * FDIM * 4);
    // pairs/clocal alias bufA: CSR build finishes before the first GEMM writes bufA
    unsigned int* pairs = (unsigned int*)bufA;
    unsigned char* clocal = (unsigned char*)(bufA) + (size_t)E * 4;

    const int gW = (N * 64 + 255) / 256;  // wave-per-node grid
    const int gG = (N + 63) / 64;         // gemm grid
    const int gZ = (NB * BSTRIDE + 255) / 256;

    // CSR build + dinv (block-reservation multisplit)
    k_zero<<<gZ, 256, 0, stream>>>(rbCnt, cbCnt, NB * BSTRIDE);
    k_count<<<NBLK, 256, 0, stream>>>(row, col, rbCnt, cbCnt, E, NB);
    k_bscan<<<1, 1024, 0, stream>>>(rbCnt, cbCnt, rbBase, cbBase, rbCur, cbCur, NB, E);
    k_scatter2<<<NBLK, 256, 0, stream>>>(row, col, rbCur, cbCur, pairs, clocal, E, NB);
    k_rowsort<<<NB, 256, 0, stream>>>(rbBase, pairs, row_ptr, csr_col, N, NB);
    k_colhist<<<NB, 256, 0, stream>>>(cbBase, clocal, dinv, N);

    // layer 0: hs0 = (x@W0 + b0)*dinv  -> bufA ; agg -> d_out (with relu)
    k_gemm<<<gG, 256, 0, stream>>>(x, W0, b0, dinv, bufA, N);
    k_agg<<<gW, 256, 0, stream>>>(bufA, row_ptr, csr_col, dinv, out, N, 1);

    // layer 1: hs1 = (out@W1 + b1)*dinv -> bufA ; agg -> d_out (no relu)
    k_gemm<<<gG, 256, 0, stream>>>(out, W1, b1, dinv, bufA, N);
    k_agg<<<gW, 256, 0, stream>>>(bufA, row_ptr, csr_col, dinv, out, N, 0);

    // log_softmax in place on d_out
    k_lsm<<<gW, 256, 0, stream>>>(out, N);
}

// Round 7
// 441.900 us; speedup vs baseline: 1.7517x; 1.2605x over previous
//
#include <hip/hip_runtime.h>
#include <math.h>

#define FDIM 128
#define RPB 128      // rows per bucket (bucket = id >> 7)
#define BSTRIDE 32   // ints per bucket counter (128 B) — one cache line per counter
#define NBLK 256     // blocks in count/scatter multisplit
#define MAXB 1024    // max buckets (N <= 131072)

static __device__ __forceinline__ unsigned short f2bf(float f) {
    unsigned int u = __float_as_uint(f);
    u = (u + 0x7fff + ((u >> 16) & 1)) >> 16;   // round-to-nearest-even
    return (unsigned short)u;
}

// ---------------- CSR build: block-reservation multisplit ----------------

__global__ __launch_bounds__(256) void k_zero(int* rbCnt, int* cbCnt, int nbs) {
    int i = blockIdx.x * 256 + threadIdx.x;
    if (i < nbs) { rbCnt[i] = 0; cbCnt[i] = 0; }
}

// per-block LDS histograms over buckets, one padded-counter flush per block
__global__ __launch_bounds__(256) void k_count(const int* __restrict__ row, const int* __restrict__ col,
                                               int* rbCnt, int* cbCnt, int nE, int nb) {
    __shared__ int rh[MAXB];
    __shared__ int ch[MAXB];
    const int tid = threadIdx.x;
    const int cpb = (nE + NBLK - 1) / NBLK;
    const int e0 = blockIdx.x * cpb;
    int e1 = e0 + cpb; if (e1 > nE) e1 = nE;
    for (int i = tid; i < nb; i += 256) { rh[i] = 0; ch[i] = 0; }
    __syncthreads();
    for (int e = e0 + tid; e < e1; e += 256) {
        atomicAdd(&rh[row[e] >> 7], 1);
        atomicAdd(&ch[col[e] >> 7], 1);
    }
    __syncthreads();
    for (int i = tid; i < nb; i += 256) {
        if (rh[i]) atomicAdd(&rbCnt[(size_t)i * BSTRIDE], rh[i]);
        if (ch[i]) atomicAdd(&cbCnt[(size_t)i * BSTRIDE], ch[i]);
    }
}

// one-block exclusive scan of both bucket-count arrays; seeds bases and cursors
__global__ __launch_bounds__(1024) void k_bscan(const int* __restrict__ rbCnt, const int* __restrict__ cbCnt,
                                                int* rbBase, int* cbBase, int* rbCur, int* cbCur,
                                                int nb, int nE) {
    __shared__ int s[1024];
    int tid = threadIdx.x;
    int v = (tid < nb) ? rbCnt[(size_t)tid * BSTRIDE] : 0;
    s[tid] = v;
    __syncthreads();
    for (int off = 1; off < 1024; off <<= 1) {
        int t = (tid >= off) ? s[tid - off] : 0;
        __syncthreads();
        s[tid] += t;
        __syncthreads();
    }
    if (tid < nb) {
        int ex = s[tid] - v;
        rbBase[tid] = ex;
        rbCur[(size_t)tid * BSTRIDE] = ex;
    }
    if (tid == 0) rbBase[nb] = nE;
    __syncthreads();
    v = (tid < nb) ? cbCnt[(size_t)tid * BSTRIDE] : 0;
    s[tid] = v;
    __syncthreads();
    for (int off = 1; off < 1024; off <<= 1) {
        int t = (tid >= off) ? s[tid - off] : 0;
        __syncthreads();
        s[tid] += t;
        __syncthreads();
    }
    if (tid < nb) {
        int ex = s[tid] - v;
        cbBase[tid] = ex;
        cbCur[(size_t)tid * BSTRIDE] = ex;
    }
    if (tid == 0) cbBase[nb] = nE;
}

// block-reservation scatter: LDS histogram -> one global reservation per
// (block,bucket) -> contiguous runs per bucket (single-producer sectors).
__global__ __launch_bounds__(256) void k_scatter2(const int* __restrict__ row, const int* __restrict__ col,
                                                  int* rbCur, int* cbCur,
                                                  unsigned int* __restrict__ pairs,
                                                  unsigned char* __restrict__ clocal, int nE, int nb) {
    __shared__ int rh[MAXB];
    __shared__ int ch[MAXB];
    __shared__ int rbase[MAXB];
    __shared__ int cbase[MAXB];
    const int tid = threadIdx.x;
    const int cpb = (nE + NBLK - 1) / NBLK;
    const int e0 = blockIdx.x * cpb;
    int e1 = e0 + cpb; if (e1 > nE) e1 = nE;

    for (int i = tid; i < nb; i += 256) { rh[i] = 0; ch[i] = 0; }
    __syncthreads();
    for (int e = e0 + tid; e < e1; e += 256) {
        atomicAdd(&rh[row[e] >> 7], 1);
        atomicAdd(&ch[col[e] >> 7], 1);
    }
    __syncthreads();
    for (int i = tid; i < nb; i += 256) {
        rbase[i] = rh[i] ? atomicAdd(&rbCur[(size_t)i * BSTRIDE], rh[i]) : 0;
        cbase[i] = ch[i] ? atomicAdd(&cbCur[(size_t)i * BSTRIDE], ch[i]) : 0;
        rh[i] = 0;
        ch[i] = 0;
    }
    __syncthreads();
    for (int e = e0 + tid; e < e1; e += 256) {
        int r = row[e];
        int c = col[e];
        int rb = r >> 7, cb = c >> 7;
        int p = rbase[rb] + atomicAdd(&rh[rb], 1);
        pairs[p] = ((unsigned int)(r & (RPB - 1)) << 25) | (unsigned int)c;
        int q = cbase[cb] + atomicAdd(&ch[cb], 1);
        clocal[q] = (unsigned char)(c & (RPB - 1));
    }
}

// per row-bucket: LDS histogram -> LDS scan -> row_ptr (coalesced) + csr_col placement
__global__ __launch_bounds__(256) void k_rowsort(const int* __restrict__ rbBase,
                                                 const unsigned int* __restrict__ pairs,
                                                 int* __restrict__ row_ptr, int* __restrict__ csr_col,
                                                 int n, int nb) {
    __shared__ int hist[RPB];
    __shared__ int scan[RPB];
    __shared__ int lcur[RPB];
    const int b = blockIdx.x;
    const int tid = threadIdx.x;
    const int row0 = b * RPB;
    const int start = rbBase[b];
    const int endp = rbBase[b + 1];

    if (tid < RPB) hist[tid] = 0;
    __syncthreads();
    for (int i = start + tid; i < endp; i += 256)
        atomicAdd(&hist[pairs[i] >> 25], 1);
    __syncthreads();

    if (tid < RPB) scan[tid] = hist[tid];
    __syncthreads();
    for (int off = 1; off < RPB; off <<= 1) {
        int t = (tid < RPB && tid >= off) ? scan[tid - off] : 0;
        __syncthreads();
        if (tid < RPB) scan[tid] += t;
        __syncthreads();
    }
    if (tid < RPB) {
        int ex = start + scan[tid] - hist[tid];
        lcur[tid] = ex;
        int r = row0 + tid;
        if (r < n) row_ptr[r] = ex;
    }
    if (b == nb - 1 && tid == 0) row_ptr[n] = endp;
    __syncthreads();

    for (int i = start + tid; i < endp; i += 256) {
        unsigned int u = pairs[i];
        int pos = atomicAdd(&lcur[u >> 25], 1);
        csr_col[pos] = (int)(u & 0x1FFFFFFu);
    }
}

// per col-bucket: LDS histogram of local col bytes -> dinv directly
__global__ __launch_bounds__(256) void k_colhist(const int* __restrict__ cbBase,
                                                 const unsigned char* __restrict__ clocal,
                                                 float* __restrict__ dinv, int n) {
    __shared__ int hist[RPB];
    const int b = blockIdx.x;
    const int tid = threadIdx.x;
    const int start = cbBase[b];
    const int endp = cbBase[b + 1];
    if (tid < RPB) hist[tid] = 0;
    __syncthreads();
    for (int i = start + tid; i < endp; i += 256)
        atomicAdd(&hist[(int)clocal[i]], 1);
    __syncthreads();
    if (tid < RPB) {
        int c = b * RPB + tid;
        if (c < n) dinv[c] = rsqrtf((float)hist[tid] + 1.0f);
    }
}

// ---------------- GEMM: hs[r][c] = bf16((sum_k X[r][k]*W[k][c] + bias[c]) * dinv[r]) ----------------
// 64 rows x 128 cols per block, 256 threads, 4x8 acc per thread, k-tile 32. bf16 output.

__global__ __launch_bounds__(256) void k_gemm(const float* __restrict__ X, const float* __restrict__ W,
                                              const float* __restrict__ bias, const float* __restrict__ dinv,
                                              unsigned short* __restrict__ out, int nRows) {
    __shared__ float sX[32][68];   // [k][row], padded
    __shared__ float sW[32][132];  // [k][col], padded

    const int tid = threadIdx.x;
    const int row0 = blockIdx.x * 64;
    const int rb = (tid >> 4) * 4;   // 0..60
    const int cb = (tid & 15) * 8;   // 0..120

    float acc[4][8];
#pragma unroll
    for (int i = 0; i < 4; i++)
#pragma unroll
        for (int j = 0; j < 8; j++) acc[i][j] = 0.0f;

    for (int k0 = 0; k0 < FDIM; k0 += 32) {
#pragma unroll
        for (int it = 0; it < 2; it++) {
            int f = tid + it * 256;
            int r = f >> 3;
            int kq = (f & 7) * 4;
            float4 v = make_float4(0.f, 0.f, 0.f, 0.f);
            int gr = row0 + r;
            if (gr < nRows) v = *(const float4*)&X[(size_t)gr * FDIM + k0 + kq];
            sX[kq + 0][r] = v.x;
            sX[kq + 1][r] = v.y;
            sX[kq + 2][r] = v.z;
            sX[kq + 3][r] = v.w;
        }
#pragma unroll
        for (int it = 0; it < 4; it++) {
            int f = tid + it * 256;
            int k = f >> 5;
            int cq = (f & 31) * 4;
            float4 v = *(const float4*)&W[(size_t)(k0 + k) * FDIM + cq];
            *(float4*)&sW[k][cq] = v;
        }
        __syncthreads();
#pragma unroll 4
        for (int kk = 0; kk < 32; kk++) {
            float4 xv = *(const float4*)&sX[kk][rb];
            float wv[8];
            *(float4*)&wv[0] = *(const float4*)&sW[kk][cb];
            *(float4*)&wv[4] = *(const float4*)&sW[kk][cb + 4];
            float xs[4] = {xv.x, xv.y, xv.z, xv.w};
#pragma unroll
            for (int i = 0; i < 4; i++)
#pragma unroll
                for (int j = 0; j < 8; j++) acc[i][j] += xs[i] * wv[j];
        }
        __syncthreads();
    }

    float bv[8];
    *(float4*)&bv[0] = *(const float4*)&bias[cb];
    *(float4*)&bv[4] = *(const float4*)&bias[cb + 4];

#pragma unroll
    for (int i = 0; i < 4; i++) {
        int gr = row0 + rb + i;
        if (gr < nRows) {
            float di = dinv[gr];
            unsigned int p[4];
#pragma unroll
            for (int j = 0; j < 4; j++) {
                unsigned int lo = f2bf((acc[i][2 * j] + bv[2 * j]) * di);
                unsigned int hi = f2bf((acc[i][2 * j + 1] + bv[2 * j + 1]) * di);
                p[j] = lo | (hi << 16);
            }
            *(uint4*)&out[(size_t)gr * FDIM + cb] = make_uint4(p[0], p[1], p[2], p[3]);
        }
    }
}

// ---------------- Aggregation: out[i] = dinv[i]*(hs[i] + sum_{e in row i} hs[col[e]]) ----------------
// hs is bf16-packed (uint = 2 bf16 per lane). Optional fused relu or log_softmax.

static __device__ __forceinline__ void bf2f(unsigned int u, float& a, float& b) {
    a = __uint_as_float(u << 16);
    b = __uint_as_float(u & 0xffff0000u);
}

__global__ __launch_bounds__(256) void k_agg(const unsigned int* __restrict__ hs, const int* __restrict__ row_ptr,
                                             const int* __restrict__ csr_col, const float* __restrict__ dinv,
                                             float* __restrict__ out, int n, int relu, int lsm) {
    int w = (blockIdx.x * 256 + threadIdx.x) >> 6;
    int lane = threadIdx.x & 63;
    if (w >= n) return;
    float a0, a1;
    bf2f(hs[(size_t)w * 64 + lane], a0, a1);

    int e = row_ptr[w];
    const int end = row_ptr[w + 1];

    while (e < end) {
        int cnt = end - e;
        if (cnt > 64) cnt = 64;
        int jv = (e + lane < end) ? csr_col[e + lane] : 0;
        int t = 0;
        for (; t + 8 <= cnt; t += 8) {
            int j0 = __shfl(jv, t + 0, 64);
            int j1 = __shfl(jv, t + 1, 64);
            int j2 = __shfl(jv, t + 2, 64);
            int j3 = __shfl(jv, t + 3, 64);
            int j4 = __shfl(jv, t + 4, 64);
            int j5 = __shfl(jv, t + 5, 64);
            int j6 = __shfl(jv, t + 6, 64);
            int j7 = __shfl(jv, t + 7, 64);
            unsigned int u0 = hs[(size_t)j0 * 64 + lane];
            unsigned int u1 = hs[(size_t)j1 * 64 + lane];
            unsigned int u2 = hs[(size_t)j2 * 64 + lane];
            unsigned int u3 = hs[(size_t)j3 * 64 + lane];
            unsigned int u4 = hs[(size_t)j4 * 64 + lane];
            unsigned int u5 = hs[(size_t)j5 * 64 + lane];
            unsigned int u6 = hs[(size_t)j6 * 64 + lane];
            unsigned int u7 = hs[(size_t)j7 * 64 + lane];
            float x0, y0, x1, y1, x2, y2, x3, y3, x4, y4, x5, y5, x6, y6, x7, y7;
            bf2f(u0, x0, y0); bf2f(u1, x1, y1); bf2f(u2, x2, y2); bf2f(u3, x3, y3);
            bf2f(u4, x4, y4); bf2f(u5, x5, y5); bf2f(u6, x6, y6); bf2f(u7, x7, y7);
            a0 += ((x0 + x1) + (x2 + x3)) + ((x4 + x5) + (x6 + x7));
            a1 += ((y0 + y1) + (y2 + y3)) + ((y4 + y5) + (y6 + y7));
        }
        for (; t < cnt; t++) {
            int j = __shfl(jv, t, 64);
            float ux, uy;
            bf2f(hs[(size_t)j * 64 + lane], ux, uy);
            a0 += ux;
            a1 += uy;
        }
        e += cnt;
    }

    float di = dinv[w];
    a0 *= di;
    a1 *= di;
    if (relu) {
        a0 = fmaxf(a0, 0.0f);
        a1 = fmaxf(a1, 0.0f);
    }
    if (lsm) {
        float m = fmaxf(a0, a1);
#pragma unroll
        for (int off = 32; off > 0; off >>= 1) m = fmaxf(m, __shfl_xor(m, off, 64));
        float s = expf(a0 - m) + expf(a1 - m);
#pragma unroll
        for (int off = 32; off > 0; off >>= 1) s += __shfl_xor(s, off, 64);
        float lg = m + logf(s);
        a0 -= lg;
        a1 -= lg;
    }
    ((float2*)out)[(size_t)w * 64 + lane] = make_float2(a0, a1);
}

// ---------------- launch ----------------

extern "C" void kernel_launch(void* const* d_in, const int* in_sizes, int n_in,
                              void* d_out, int out_size, void* d_ws, size_t ws_size,
                              hipStream_t stream) {
    const float* x  = (const float*)d_in[0];
    const float* W0 = (const float*)d_in[1];
    const float* b0 = (const float*)d_in[2];
    const float* W1 = (const float*)d_in[3];
    const float* b1 = (const float*)d_in[4];
    const int* row  = (const int*)d_in[5];
    const int* col  = (const int*)d_in[6];
    float* out = (float*)d_out;

    const int N = in_sizes[0] / FDIM;
    const int E = in_sizes[5];
    const int NB = (N + RPB - 1) / RPB;  // buckets (782 for N=100000)

    char* w = (char*)d_ws;
    size_t off = 0;
    auto alloc = [&](size_t bytes) {
        char* p = w + off;
        off += (bytes + 255) & ~(size_t)255;
        return p;
    };
    int* rbCnt   = (int*)alloc((size_t)NB * BSTRIDE * 4);
    int* cbCnt   = (int*)alloc((size_t)NB * BSTRIDE * 4);
    int* rbCur   = (int*)alloc((size_t)NB * BSTRIDE * 4);
    int* cbCur   = (int*)alloc((size_t)NB * BSTRIDE * 4);
    int* rbBase  = (int*)alloc((size_t)(NB + 1) * 4);
    int* cbBase  = (int*)alloc((size_t)(NB + 1) * 4);
    float* dinv  = (float*)alloc((size_t)N * 4);
    int* row_ptr = (int*)alloc((size_t)(N + 1) * 4);
    int* csr_col = (int*)alloc((size_t)E * 4);
    unsigned short* bufA = (unsigned short*)alloc((size_t)N * FDIM * 2);  // bf16 hs
    // pairs/clocal get their own region (bufA is only 25.6MB; keep them separate for safety)
    unsigned int* pairs = (unsigned int*)alloc((size_t)E * 4);
    unsigned char* clocal = (unsigned char*)alloc((size_t)E);

    const int gW = (N * 64 + 255) / 256;  // wave-per-node grid
    const int gG = (N + 63) / 64;         // gemm grid
    const int gZ = (NB * BSTRIDE + 255) / 256;

    // CSR build + dinv (block-reservation multisplit)
    k_zero<<<gZ, 256, 0, stream>>>(rbCnt, cbCnt, NB * BSTRIDE);
    k_count<<<NBLK, 256, 0, stream>>>(row, col, rbCnt, cbCnt, E, NB);
    k_bscan<<<1, 1024, 0, stream>>>(rbCnt, cbCnt, rbBase, cbBase, rbCur, cbCur, NB, E);
    k_scatter2<<<NBLK, 256, 0, stream>>>(row, col, rbCur, cbCur, pairs, clocal, E, NB);
    k_rowsort<<<NB, 256, 0, stream>>>(rbBase, pairs, row_ptr, csr_col, N, NB);
    k_colhist<<<NB, 256, 0, stream>>>(cbBase, clocal, dinv, N);

    // layer 0: hs0 = bf16((x@W0 + b0)*dinv) -> bufA ; agg -> d_out (relu)
    k_gemm<<<gG, 256, 0, stream>>>(x, W0, b0, dinv, bufA, N);
    k_agg<<<gW, 256, 0, stream>>>((const unsigned int*)bufA, row_ptr, csr_col, dinv, out, N, 1, 0);

    // layer 1: hs1 = bf16((out@W1 + b1)*dinv) -> bufA ; agg+log_softmax -> d_out
    k_gemm<<<gG, 256, 0, stream>>>(out, W1, b1, dinv, bufA, N);
    k_agg<<<gW, 256, 0, stream>>>((const unsigned int*)bufA, row_ptr, csr_col, dinv, out, N, 0, 1);
}

// Round 8
// 412.483 us; speedup vs baseline: 1.8767x; 1.0713x over previous
//
#include <hip/hip_runtime.h>
#include <math.h>

#define FDIM 128
#define RPB 128      // rows per bucket (bucket = id >> 7)
#define BSTRIDE 32   // ints per bucket counter (128 B) — one cache line per counter
#define NBLK 256     // blocks in count/scatter multisplit
#define MAXB 1024    // max buckets (N <= 131072)

typedef __attribute__((ext_vector_type(8))) short short8;   // 8 bf16 (4 VGPRs)
typedef __attribute__((ext_vector_type(4))) float floatx4;  // 4 fp32 acc

static __device__ __forceinline__ unsigned short f2bf(float f) {
    unsigned int u = __float_as_uint(f);
    u = (u + 0x7fff + ((u >> 16) & 1)) >> 16;   // round-to-nearest-even
    return (unsigned short)u;
}

static __device__ __forceinline__ void bf2f(unsigned int u, float& a, float& b) {
    a = __uint_as_float(u << 16);
    b = __uint_as_float(u & 0xffff0000u);
}

// ---------------- CSR build: block-reservation multisplit ----------------

__global__ __launch_bounds__(256) void k_zero(int* rbCnt, int* cbCnt, int nbs) {
    int i = blockIdx.x * 256 + threadIdx.x;
    if (i < nbs) { rbCnt[i] = 0; cbCnt[i] = 0; }
}

__global__ __launch_bounds__(256) void k_count(const int* __restrict__ row, const int* __restrict__ col,
                                               int* rbCnt, int* cbCnt, int nE, int nb) {
    __shared__ int rh[MAXB];
    __shared__ int ch[MAXB];
    const int tid = threadIdx.x;
    const int cpb = (nE + NBLK - 1) / NBLK;
    const int e0 = blockIdx.x * cpb;
    int e1 = e0 + cpb; if (e1 > nE) e1 = nE;
    for (int i = tid; i < nb; i += 256) { rh[i] = 0; ch[i] = 0; }
    __syncthreads();
    for (int e = e0 + tid; e < e1; e += 256) {
        atomicAdd(&rh[row[e] >> 7], 1);
        atomicAdd(&ch[col[e] >> 7], 1);
    }
    __syncthreads();
    for (int i = tid; i < nb; i += 256) {
        if (rh[i]) atomicAdd(&rbCnt[(size_t)i * BSTRIDE], rh[i]);
        if (ch[i]) atomicAdd(&cbCnt[(size_t)i * BSTRIDE], ch[i]);
    }
}

__global__ __launch_bounds__(1024) void k_bscan(const int* __restrict__ rbCnt, const int* __restrict__ cbCnt,
                                                int* rbBase, int* cbBase, int* rbCur, int* cbCur,
                                                int nb, int nE) {
    __shared__ int s[1024];
    int tid = threadIdx.x;
    int v = (tid < nb) ? rbCnt[(size_t)tid * BSTRIDE] : 0;
    s[tid] = v;
    __syncthreads();
    for (int off = 1; off < 1024; off <<= 1) {
        int t = (tid >= off) ? s[tid - off] : 0;
        __syncthreads();
        s[tid] += t;
        __syncthreads();
    }
    if (tid < nb) {
        int ex = s[tid] - v;
        rbBase[tid] = ex;
        rbCur[(size_t)tid * BSTRIDE] = ex;
    }
    if (tid == 0) rbBase[nb] = nE;
    __syncthreads();
    v = (tid < nb) ? cbCnt[(size_t)tid * BSTRIDE] : 0;
    s[tid] = v;
    __syncthreads();
    for (int off = 1; off < 1024; off <<= 1) {
        int t = (tid >= off) ? s[tid - off] : 0;
        __syncthreads();
        s[tid] += t;
        __syncthreads();
    }
    if (tid < nb) {
        int ex = s[tid] - v;
        cbBase[tid] = ex;
        cbCur[(size_t)tid * BSTRIDE] = ex;
    }
    if (tid == 0) cbBase[nb] = nE;
}

__global__ __launch_bounds__(256) void k_scatter2(const int* __restrict__ row, const int* __restrict__ col,
                                                  int* rbCur, int* cbCur,
                                                  unsigned int* __restrict__ pairs,
                                                  unsigned char* __restrict__ clocal, int nE, int nb) {
    __shared__ int rh[MAXB];
    __shared__ int ch[MAXB];
    __shared__ int rbase[MAXB];
    __shared__ int cbase[MAXB];
    const int tid = threadIdx.x;
    const int cpb = (nE + NBLK - 1) / NBLK;
    const int e0 = blockIdx.x * cpb;
    int e1 = e0 + cpb; if (e1 > nE) e1 = nE;

    for (int i = tid; i < nb; i += 256) { rh[i] = 0; ch[i] = 0; }
    __syncthreads();
    for (int e = e0 + tid; e < e1; e += 256) {
        atomicAdd(&rh[row[e] >> 7], 1);
        atomicAdd(&ch[col[e] >> 7], 1);
    }
    __syncthreads();
    for (int i = tid; i < nb; i += 256) {
        rbase[i] = rh[i] ? atomicAdd(&rbCur[(size_t)i * BSTRIDE], rh[i]) : 0;
        cbase[i] = ch[i] ? atomicAdd(&cbCur[(size_t)i * BSTRIDE], ch[i]) : 0;
        rh[i] = 0;
        ch[i] = 0;
    }
    __syncthreads();
    for (int e = e0 + tid; e < e1; e += 256) {
        int r = row[e];
        int c = col[e];
        int rb = r >> 7, cb = c >> 7;
        int p = rbase[rb] + atomicAdd(&rh[rb], 1);
        pairs[p] = ((unsigned int)(r & (RPB - 1)) << 25) | (unsigned int)c;
        int q = cbase[cb] + atomicAdd(&ch[cb], 1);
        clocal[q] = (unsigned char)(c & (RPB - 1));
    }
}

__global__ __launch_bounds__(256) void k_rowsort(const int* __restrict__ rbBase,
                                                 const unsigned int* __restrict__ pairs,
                                                 int* __restrict__ row_ptr, int* __restrict__ csr_col,
                                                 int n, int nb) {
    __shared__ int hist[RPB];
    __shared__ int scan[RPB];
    __shared__ int lcur[RPB];
    const int b = blockIdx.x;
    const int tid = threadIdx.x;
    const int row0 = b * RPB;
    const int start = rbBase[b];
    const int endp = rbBase[b + 1];

    if (tid < RPB) hist[tid] = 0;
    __syncthreads();
    for (int i = start + tid; i < endp; i += 256)
        atomicAdd(&hist[pairs[i] >> 25], 1);
    __syncthreads();

    if (tid < RPB) scan[tid] = hist[tid];
    __syncthreads();
    for (int off = 1; off < RPB; off <<= 1) {
        int t = (tid < RPB && tid >= off) ? scan[tid - off] : 0;
        __syncthreads();
        if (tid < RPB) scan[tid] += t;
        __syncthreads();
    }
    if (tid < RPB) {
        int ex = start + scan[tid] - hist[tid];
        lcur[tid] = ex;
        int r = row0 + tid;
        if (r < n) row_ptr[r] = ex;
    }
    if (b == nb - 1 && tid == 0) row_ptr[n] = endp;
    __syncthreads();

    for (int i = start + tid; i < endp; i += 256) {
        unsigned int u = pairs[i];
        int pos = atomicAdd(&lcur[u >> 25], 1);
        csr_col[pos] = (int)(u & 0x1FFFFFFu);
    }
}

__global__ __launch_bounds__(256) void k_colhist(const int* __restrict__ cbBase,
                                                 const unsigned char* __restrict__ clocal,
                                                 float* __restrict__ dinv, int n) {
    __shared__ int hist[RPB];
    const int b = blockIdx.x;
    const int tid = threadIdx.x;
    const int start = cbBase[b];
    const int endp = cbBase[b + 1];
    if (tid < RPB) hist[tid] = 0;
    __syncthreads();
    for (int i = start + tid; i < endp; i += 256)
        atomicAdd(&hist[(int)clocal[i]], 1);
    __syncthreads();
    if (tid < RPB) {
        int c = b * RPB + tid;
        if (c < n) dinv[c] = rsqrtf((float)hist[tid] + 1.0f);
    }
}

// ---------------- converters ----------------

// x fp32 -> packed bf16 (2 per uint)
__global__ __launch_bounds__(256) void k_cvt(const float2* __restrict__ x, unsigned int* __restrict__ xb,
                                             int total) {
    int i = blockIdx.x * 256 + threadIdx.x;
    if (i < total) {
        float2 v = x[i];
        xb[i] = (unsigned int)f2bf(v.x) | ((unsigned int)f2bf(v.y) << 16);
    }
}

// W (K x N fp32) -> Wt (N x K bf16), both 128x128; block 0 = W0, block 1 = W1
__global__ __launch_bounds__(256) void k_cvtW(const float* __restrict__ W0, const float* __restrict__ W1,
                                              unsigned short* __restrict__ W0t, unsigned short* __restrict__ W1t) {
    const float* W = blockIdx.x ? W1 : W0;
    unsigned short* Wt = blockIdx.x ? W1t : W0t;
    for (int idx = threadIdx.x; idx < FDIM * FDIM; idx += 256) {
        int k = idx >> 7, c = idx & 127;
        Wt[c * FDIM + k] = f2bf(W[idx]);
    }
}

// ---------------- MFMA GEMM: hs[r][c] = bf16((A[r][:] @ W[:,c] + bias[c]) * dinv[r]) ----------------
// A: N x 128 bf16 row-major. Wt: 128 x 128 bf16, Wt[n][k]. Output packed bf16 (2/uint).
// 128 rows/block, 4 waves in 2x2, each wave 64x64 via 4x4 16x16x32 tiles; K staged in 2 halves.

#define KH 64            // K half
#define LPAD 72          // LDS row stride in shorts (64 + 8 pad; 2-way bank alias = free)

__global__ __launch_bounds__(256) void k_gemm_mfma(const unsigned short* __restrict__ A,
                                                   const unsigned short* __restrict__ Wt,
                                                   const float* __restrict__ bias,
                                                   const float* __restrict__ dinv,
                                                   unsigned int* __restrict__ outp, int n) {
    __shared__ unsigned short sA[128][LPAD];
    __shared__ unsigned short sW[128][LPAD];

    const int tid = threadIdx.x;
    const int row0 = blockIdx.x * 128;
    const int wid = tid >> 6;
    const int lane = tid & 63;
    const int quad = lane >> 4;
    const int lq = lane & 15;
    const int wm = wid & 1;        // row half
    const int wn = wid >> 1;       // col half

    floatx4 acc[4][4];
#pragma unroll
    for (int i = 0; i < 4; i++)
#pragma unroll
        for (int j = 0; j < 4; j++) acc[i][j] = (floatx4){0.f, 0.f, 0.f, 0.f};

    for (int kh = 0; kh < 2; kh++) {
        if (kh) __syncthreads();
        // stage A rows [row0,row0+128) cols [kh*64, +64), and Wt rows (all n) same k window
#pragma unroll
        for (int it = 0; it < 4; it++) {
            int f = tid + it * 256;          // 0..1023
            int r = f >> 3;                  // 0..127
            int c8 = (f & 7) * 8;            // 0..56
            int gr = row0 + r;
            uint4 v = make_uint4(0u, 0u, 0u, 0u);
            if (gr < n) v = *(const uint4*)&A[(size_t)gr * FDIM + kh * KH + c8];
            *(uint4*)&sA[r][c8] = v;
            uint4 wv = *(const uint4*)&Wt[(size_t)r * FDIM + kh * KH + c8];
            *(uint4*)&sW[r][c8] = wv;
        }
        __syncthreads();

#pragma unroll
        for (int kt = 0; kt < 2; kt++) {
            const int k0 = kt * 32 + quad * 8;
            short8 af[4], bf[4];
#pragma unroll
            for (int mt = 0; mt < 4; mt++)
                af[mt] = *(const short8*)&sA[wm * 64 + mt * 16 + lq][k0];
#pragma unroll
            for (int nt = 0; nt < 4; nt++)
                bf[nt] = *(const short8*)&sW[wn * 64 + nt * 16 + lq][k0];
#pragma unroll
            for (int mt = 0; mt < 4; mt++)
#pragma unroll
                for (int nt = 0; nt < 4; nt++)
                    acc[mt][nt] = __builtin_amdgcn_mfma_f32_16x16x32_bf16(af[mt], bf[nt], acc[mt][nt], 0, 0, 0);
        }
    }

    // epilogue: D row = quad*4+reg, col = lq (per 16x16 tile)
    float bv[4];
#pragma unroll
    for (int nt = 0; nt < 4; nt++) bv[nt] = bias[wn * 64 + nt * 16 + lq];

#pragma unroll
    for (int mt = 0; mt < 4; mt++) {
#pragma unroll
        for (int r = 0; r < 4; r++) {
            int grow = row0 + wm * 64 + mt * 16 + quad * 4 + r;
            float di = (grow < n) ? dinv[grow] : 0.f;
#pragma unroll
            for (int nt = 0; nt < 4; nt++) {
                float v = (acc[mt][nt][r] + bv[nt]) * di;
                float pv = __shfl_xor(v, 1, 64);
                if (!(lq & 1) && grow < n) {
                    int col = wn * 64 + nt * 16 + lq;
                    outp[(size_t)grow * 64 + (col >> 1)] =
                        (unsigned int)f2bf(v) | ((unsigned int)f2bf(pv) << 16);
                }
            }
        }
    }
}

// ---------------- Aggregation: out[i] = dinv[i]*(hs[i] + sum_{e in row i} hs[col[e]]) ----------------
// hs packed bf16. obf: write packed bf16; else fp32 float2. Optional fused relu / log_softmax.

__global__ __launch_bounds__(256) void k_agg(const unsigned int* __restrict__ hs, const int* __restrict__ row_ptr,
                                             const int* __restrict__ csr_col, const float* __restrict__ dinv,
                                             void* __restrict__ out, int n, int relu, int lsm, int obf) {
    int w = (blockIdx.x * 256 + threadIdx.x) >> 6;
    int lane = threadIdx.x & 63;
    if (w >= n) return;
    float a0, a1;
    bf2f(hs[(size_t)w * 64 + lane], a0, a1);

    int e = row_ptr[w];
    const int end = row_ptr[w + 1];

    while (e < end) {
        int cnt = end - e;
        if (cnt > 64) cnt = 64;
        int jv = (e + lane < end) ? csr_col[e + lane] : 0;
        int t = 0;
        for (; t + 8 <= cnt; t += 8) {
            int j0 = __shfl(jv, t + 0, 64);
            int j1 = __shfl(jv, t + 1, 64);
            int j2 = __shfl(jv, t + 2, 64);
            int j3 = __shfl(jv, t + 3, 64);
            int j4 = __shfl(jv, t + 4, 64);
            int j5 = __shfl(jv, t + 5, 64);
            int j6 = __shfl(jv, t + 6, 64);
            int j7 = __shfl(jv, t + 7, 64);
            unsigned int u0 = hs[(size_t)j0 * 64 + lane];
            unsigned int u1 = hs[(size_t)j1 * 64 + lane];
            unsigned int u2 = hs[(size_t)j2 * 64 + lane];
            unsigned int u3 = hs[(size_t)j3 * 64 + lane];
            unsigned int u4 = hs[(size_t)j4 * 64 + lane];
            unsigned int u5 = hs[(size_t)j5 * 64 + lane];
            unsigned int u6 = hs[(size_t)j6 * 64 + lane];
            unsigned int u7 = hs[(size_t)j7 * 64 + lane];
            float x0, y0, x1, y1, x2, y2, x3, y3, x4, y4, x5, y5, x6, y6, x7, y7;
            bf2f(u0, x0, y0); bf2f(u1, x1, y1); bf2f(u2, x2, y2); bf2f(u3, x3, y3);
            bf2f(u4, x4, y4); bf2f(u5, x5, y5); bf2f(u6, x6, y6); bf2f(u7, x7, y7);
            a0 += ((x0 + x1) + (x2 + x3)) + ((x4 + x5) + (x6 + x7));
            a1 += ((y0 + y1) + (y2 + y3)) + ((y4 + y5) + (y6 + y7));
        }
        for (; t < cnt; t++) {
            int j = __shfl(jv, t, 64);
            float ux, uy;
            bf2f(hs[(size_t)j * 64 + lane], ux, uy);
            a0 += ux;
            a1 += uy;
        }
        e += cnt;
    }

    float di = dinv[w];
    a0 *= di;
    a1 *= di;
    if (relu) {
        a0 = fmaxf(a0, 0.0f);
        a1 = fmaxf(a1, 0.0f);
    }
    if (lsm) {
        float m = fmaxf(a0, a1);
#pragma unroll
        for (int off = 32; off > 0; off >>= 1) m = fmaxf(m, __shfl_xor(m, off, 64));
        float s = expf(a0 - m) + expf(a1 - m);
#pragma unroll
        for (int off = 32; off > 0; off >>= 1) s += __shfl_xor(s, off, 64);
        float lg = m + logf(s);
        a0 -= lg;
        a1 -= lg;
    }
    if (obf) {
        ((unsigned int*)out)[(size_t)w * 64 + lane] =
            (unsigned int)f2bf(a0) | ((unsigned int)f2bf(a1) << 16);
    } else {
        ((float2*)out)[(size_t)w * 64 + lane] = make_float2(a0, a1);
    }
}

// ---------------- launch ----------------

extern "C" void kernel_launch(void* const* d_in, const int* in_sizes, int n_in,
                              void* d_out, int out_size, void* d_ws, size_t ws_size,
                              hipStream_t stream) {
    const float* x  = (const float*)d_in[0];
    const float* W0 = (const float*)d_in[1];
    const float* b0 = (const float*)d_in[2];
    const float* W1 = (const float*)d_in[3];
    const float* b1 = (const float*)d_in[4];
    const int* row  = (const int*)d_in[5];
    const int* col  = (const int*)d_in[6];
    float* out = (float*)d_out;

    const int N = in_sizes[0] / FDIM;
    const int E = in_sizes[5];
    const int NB = (N + RPB - 1) / RPB;  // buckets (782 for N=100000)

    char* w = (char*)d_ws;
    size_t off = 0;
    auto alloc = [&](size_t bytes) {
        char* p = w + off;
        off += (bytes + 255) & ~(size_t)255;
        return p;
    };
    int* rbCnt   = (int*)alloc((size_t)NB * BSTRIDE * 4);
    int* cbCnt   = (int*)alloc((size_t)NB * BSTRIDE * 4);
    int* rbCur   = (int*)alloc((size_t)NB * BSTRIDE * 4);
    int* cbCur   = (int*)alloc((size_t)NB * BSTRIDE * 4);
    int* rbBase  = (int*)alloc((size_t)(NB + 1) * 4);
    int* cbBase  = (int*)alloc((size_t)(NB + 1) * 4);
    float* dinv  = (float*)alloc((size_t)N * 4);
    int* row_ptr = (int*)alloc((size_t)(N + 1) * 4);
    int* csr_col = (int*)alloc((size_t)E * 4);
    unsigned short* W0t = (unsigned short*)alloc((size_t)FDIM * FDIM * 2);
    unsigned short* W1t = (unsigned short*)alloc((size_t)FDIM * FDIM * 2);
    unsigned int* hs = (unsigned int*)alloc((size_t)N * 64 * 4);  // packed bf16 hs
    // Union region: pairs+clocal (CSR build) -> xb (cvt->gemm0) -> hb (agg0->gemm1).
    // Each consumer finishes (stream order) before the next producer writes.
    size_t uniSz = (size_t)E * 4 + (size_t)E + 512;
    size_t xbSz  = (size_t)N * 64 * 4;
    char* uni = (char*)alloc(uniSz > xbSz ? uniSz : xbSz);
    unsigned int* pairs = (unsigned int*)uni;
    unsigned char* clocal = (unsigned char*)uni + (size_t)E * 4;
    unsigned int* xb = (unsigned int*)uni;   // bf16-packed x
    unsigned int* hb = (unsigned int*)uni;   // bf16-packed h (layer-0 output)

    const int gW = (N * 64 + 255) / 256;   // wave-per-node grid
    const int gG = (N + 127) / 128;        // mfma-gemm grid
    const int gZ = (NB * BSTRIDE + 255) / 256;
    const int gC = (N * 64 + 255) / 256;   // cvt grid

    // CSR build + dinv (block-reservation multisplit)
    k_zero<<<gZ, 256, 0, stream>>>(rbCnt, cbCnt, NB * BSTRIDE);
    k_count<<<NBLK, 256, 0, stream>>>(row, col, rbCnt, cbCnt, E, NB);
    k_bscan<<<1, 1024, 0, stream>>>(rbCnt, cbCnt, rbBase, cbBase, rbCur, cbCur, NB, E);
    k_scatter2<<<NBLK, 256, 0, stream>>>(row, col, rbCur, cbCur, pairs, clocal, E, NB);
    k_rowsort<<<NB, 256, 0, stream>>>(rbBase, pairs, row_ptr, csr_col, N, NB);
    k_colhist<<<NB, 256, 0, stream>>>(cbBase, clocal, dinv, N);

    // weights + input to bf16
    k_cvtW<<<2, 256, 0, stream>>>(W0, W1, W0t, W1t);
    k_cvt<<<gC, 256, 0, stream>>>((const float2*)x, xb, N * 64);

    // layer 0: hs0 = bf16((x@W0 + b0)*dinv) ; agg(+relu) -> hb (packed bf16)
    k_gemm_mfma<<<gG, 256, 0, stream>>>((const unsigned short*)xb, W0t, b0, dinv, hs, N);
    k_agg<<<gW, 256, 0, stream>>>(hs, row_ptr, csr_col, dinv, hb, N, 1, 0, 1);

    // layer 1: hs1 = bf16((h@W1 + b1)*dinv) ; agg(+log_softmax) -> d_out (fp32)
    k_gemm_mfma<<<gG, 256, 0, stream>>>((const unsigned short*)hb, W1t, b1, dinv, hs, N);
    k_agg<<<gW, 256, 0, stream>>>(hs, row_ptr, csr_col, dinv, out, N, 0, 1, 0);
}